// Round 3
// baseline (1994.209 us; speedup 1.0000x reference)
//
#include <hip/hip_runtime.h>

typedef __bf16 bf16x8 __attribute__((ext_vector_type(8)));
typedef float f32x4 __attribute__((ext_vector_type(4)));

__device__ inline __bf16 to_bf16(float f) {  // round-to-nearest-even
  union { float f; unsigned u; } x; x.f = f;
  unsigned r = (x.u + 0x7FFFu + ((x.u >> 16) & 1u)) >> 16;
  union { unsigned short s; __bf16 b; } y; y.s = (unsigned short)r;
  return y.b;
}

// ---------------------------------------------------------------------------
// GEMM C[M,N] = A[M,K] @ B[K,N], row-major. A/B: fp32 or bf16 (converted to
// bf16 in LDS staging); C: fp32 or bf16. fp32 accum via MFMA.
// 128x128 tile, BK=32, 4 waves 2x2, each wave 64x64 via 4x4 16x16x32 MFMAs.
// Fragment layouts (HW-verified per guide):
//   A: lane holds A[m=lane&15][k=(lane>>4)*8+j]
//   B: lane holds B[k=(lane>>4)*8+j][n=lane&15]  (Bsl stores B transposed [n][k])
//   D: reg r holds D[row=(lane>>4)*4+r][col=lane&15]
// ---------------------------------------------------------------------------
#define GBM 128
#define GBN 128
#define GBK 32
#define LDSA 40
#define LDSB 40

template <bool A_F32, bool B_F32, bool C_F32>
__global__ __launch_bounds__(256, 2) void gemm_any(
    const void* __restrict__ Ap, const void* __restrict__ Bp,
    void* __restrict__ Cp, int M, int N, int K)
{
  __shared__ __align__(16) __bf16 Asl[GBM * LDSA];
  __shared__ __align__(16) __bf16 Bsl[GBN * LDSB];
  const int tid  = threadIdx.x;
  const int wave = tid >> 6, lane = tid & 63;
  const int quad = lane >> 4, l16 = lane & 15;
  const int m0 = blockIdx.y * GBM, n0 = blockIdx.x * GBN;
  const int wm = (wave >> 1) * 64, wn = (wave & 1) * 64;

  f32x4 acc[4][4];
#pragma unroll
  for (int i = 0; i < 4; i++)
#pragma unroll
    for (int j = 0; j < 4; j++) acc[i][j] = (f32x4){0.f, 0.f, 0.f, 0.f};

  for (int k0 = 0; k0 < K; k0 += GBK) {
    __syncthreads();
    // Stage A tile (128x32) in groups of 4 elems: 1024 groups, 4/thread.
#pragma unroll
    for (int g = tid; g < (GBM * GBK) / 4; g += 256) {
      int row = g >> 3, seg = (g & 7) * 4;
      __bf16 h[4];
      if (A_F32) {
        float4 vv = *(const float4*)((const float*)Ap + (size_t)(m0 + row) * K + k0 + seg);
        h[0] = to_bf16(vv.x); h[1] = to_bf16(vv.y);
        h[2] = to_bf16(vv.z); h[3] = to_bf16(vv.w);
        *(uint2*)&Asl[row * LDSA + seg] = *(const uint2*)h;
      } else {
        *(uint2*)&Asl[row * LDSA + seg] =
            *(const uint2*)((const __bf16*)Ap + (size_t)(m0 + row) * K + k0 + seg);
      }
    }
    // Stage B tile (32x128) transposed into Bsl[n][k].
#pragma unroll
    for (int g = tid; g < (GBK * GBN) / 4; g += 256) {
      int k = g >> 5, c = g & 31;
      __bf16 h[4];
      if (B_F32) {
        float4 vv = *(const float4*)((const float*)Bp + (size_t)(k0 + k) * N + n0 + c * 4);
        h[0] = to_bf16(vv.x); h[1] = to_bf16(vv.y);
        h[2] = to_bf16(vv.z); h[3] = to_bf16(vv.w);
      } else {
        *(uint2*)h = *(const uint2*)((const __bf16*)Bp + (size_t)(k0 + k) * N + n0 + c * 4);
      }
#pragma unroll
      for (int i = 0; i < 4; i++) Bsl[(c * 4 + i) * LDSB + k] = h[i];
    }
    __syncthreads();

    bf16x8 af[4], bfr[4];
#pragma unroll
    for (int i = 0; i < 4; i++)
      af[i] = *(const bf16x8*)&Asl[(wm + i * 16 + l16) * LDSA + quad * 8];
#pragma unroll
    for (int i = 0; i < 4; i++)
      bfr[i] = *(const bf16x8*)&Bsl[(wn + i * 16 + l16) * LDSB + quad * 8];
#pragma unroll
    for (int mi = 0; mi < 4; mi++)
#pragma unroll
      for (int ni = 0; ni < 4; ni++)
        acc[mi][ni] = __builtin_amdgcn_mfma_f32_16x16x32_bf16(
            af[mi], bfr[ni], acc[mi][ni], 0, 0, 0);
  }

#pragma unroll
  for (int mi = 0; mi < 4; mi++)
#pragma unroll
    for (int ni = 0; ni < 4; ni++)
#pragma unroll
      for (int r = 0; r < 4; r++) {
        int row = m0 + wm + mi * 16 + quad * 4 + r;
        int col = n0 + wn + ni * 16 + l16;
        if (C_F32) ((float*)Cp)[(size_t)row * N + col] = acc[mi][ni][r];
        else ((__bf16*)Cp)[(size_t)row * N + col] = to_bf16(acc[mi][ni][r]);
      }
}

// ---------------------------------------------------------------------------
// MQA causal flash attention (VALU, fp32 accum), bf16 in/out.
// One block = 16 query rows of one (b,h); 4 waves x 4 rows each.
// IN-PLACE SAFE on Q==O (no __restrict__ on Q/O): block stages its q region
// into LDS first; writes O to exactly that region at the end; regions
// disjoint across blocks.
// ---------------------------------------------------------------------------
#define TQ 16
#define CK 64
#define KST 132

__global__ __launch_bounds__(256) void mqa_attn_kernel(
    const __bf16* Q, const __bf16* __restrict__ Km,
    const __bf16* __restrict__ Vm, __bf16* O, int T)
{
  __shared__ __align__(16) __bf16 Ks[CK * KST];
  __shared__ __align__(16) __bf16 Vs[CK * KST];
  __shared__ __align__(16) float qf[TQ * 128];
  __shared__ __align__(16) float pl[4][CK][4];
  const int tid = threadIdx.x, wave = tid >> 6, lane = tid & 63;
  const int qbase = blockIdx.x * TQ;
  const int h = blockIdx.y, b = blockIdx.z;
  const size_t qrow0 = (size_t)b * T + qbase;

  for (int v = tid; v < TQ * 128; v += 256) {
    int r = v >> 7, d = v & 127;
    qf[v] = (float)Q[(qrow0 + r) * 2048 + h * 128 + d];
  }

  float m[4], l[4], o0[4], o1[4];
  int qi[4];
#pragma unroll
  for (int r = 0; r < 4; r++) {
    m[r] = -INFINITY; l[r] = 0.f; o0[r] = 0.f; o1[r] = 0.f;
    qi[r] = qbase + wave * 4 + r;
  }
  const int smax = qbase + TQ - 1;
  const __bf16* Kb = Km + (size_t)b * T * 128;
  const __bf16* Vb = Vm + (size_t)b * T * 128;
  const float scale = 0.08838834764831845f;  // 1/sqrt(128)

  for (int s = 0; s <= smax; s += CK) {
    __syncthreads();
    for (int v = tid; v < 2048; v += 256) {
      int row = v >> 5, seg = (v & 31) * 4;
      *(uint2*)&Ks[row * KST + seg] =
          *(const uint2*)&Kb[(size_t)(s + row) * 128 + seg];
      *(uint2*)&Vs[row * KST + seg] =
          *(const uint2*)&Vb[(size_t)(s + row) * 128 + seg];
    }
    __syncthreads();

    float sc[4] = {0.f, 0.f, 0.f, 0.f};
    for (int d = 0; d < 128; d += 4) {
      uint2 kv = *(const uint2*)&Ks[lane * KST + d];
      float k0 = __uint_as_float(kv.x << 16);
      float k1 = __uint_as_float(kv.x & 0xffff0000u);
      float k2 = __uint_as_float(kv.y << 16);
      float k3 = __uint_as_float(kv.y & 0xffff0000u);
#pragma unroll
      for (int r = 0; r < 4; r++) {
        float4 qq = *(const float4*)&qf[(wave * 4 + r) * 128 + d];
        sc[r] = fmaf(qq.x, k0, sc[r]);
        sc[r] = fmaf(qq.y, k1, sc[r]);
        sc[r] = fmaf(qq.z, k2, sc[r]);
        sc[r] = fmaf(qq.w, k3, sc[r]);
      }
    }
    const int key = s + lane;
    float p4[4];
#pragma unroll
    for (int r = 0; r < 4; r++) {
      float sv = (key <= qi[r]) ? sc[r] * scale : -INFINITY;
      float cmax = sv;
#pragma unroll
      for (int off = 32; off > 0; off >>= 1)
        cmax = fmaxf(cmax, __shfl_xor(cmax, off, 64));
      float mnew = fmaxf(m[r], cmax);  // lane-0 key of every chunk unmasked
      float p = 0.f, alpha = 1.f;
      if (mnew > -INFINITY) {
        p = __expf(sv - mnew);
        alpha = __expf(m[r] - mnew);
      }
      float psum = p;
#pragma unroll
      for (int off = 32; off > 0; off >>= 1)
        psum += __shfl_xor(psum, off, 64);
      l[r] = l[r] * alpha + psum;
      o0[r] *= alpha; o1[r] *= alpha;
      m[r] = mnew;
      p4[r] = p;
    }
    *(float4*)&pl[wave][lane][0] = make_float4(p4[0], p4[1], p4[2], p4[3]);

#pragma unroll 4
    for (int j = 0; j < CK; j++) {
      float4 pj = *(const float4*)&pl[wave][j][0];
      unsigned int vv = *(const unsigned int*)&Vs[j * KST + lane * 2];
      float v0 = __uint_as_float(vv << 16);
      float v1 = __uint_as_float(vv & 0xffff0000u);
      o0[0] = fmaf(pj.x, v0, o0[0]); o1[0] = fmaf(pj.x, v1, o1[0]);
      o0[1] = fmaf(pj.y, v0, o0[1]); o1[1] = fmaf(pj.y, v1, o1[1]);
      o0[2] = fmaf(pj.z, v0, o0[2]); o1[2] = fmaf(pj.z, v1, o1[2]);
      o0[3] = fmaf(pj.w, v0, o0[3]); o1[3] = fmaf(pj.w, v1, o1[3]);
    }
  }

#pragma unroll
  for (int r = 0; r < 4; r++) {
    float inv = 1.f / l[r];
    size_t orow = (qrow0 + wave * 4 + r) * 2048 + h * 128 + lane * 2;
    O[orow]     = to_bf16(o0[r] * inv);
    O[orow + 1] = to_bf16(o1[r] * inv);
  }
}

// ---------------------------------------------------------------------------
// fp32 I/O (reference dtype), bf16 internals.
// ws (bf16 elems): q/at[BT*D] | k[BT*HD] | v[BT*HD]  = 18.9 MB
// ---------------------------------------------------------------------------
extern "C" void kernel_launch(void* const* d_in, const int* in_sizes, int n_in,
                              void* d_out, int out_size, void* d_ws, size_t ws_size,
                              hipStream_t stream) {
  const float* x  = (const float*)d_in[0];
  const float* Wq = (const float*)d_in[1];
  const float* Wk = (const float*)d_in[2];
  const float* Wv = (const float*)d_in[3];
  const float* Wo = (const float*)d_in[4];
  float* out = (float*)d_out;

  const int Bsz = 2, T = 2048, D = 2048, H = 16, HD = 128;
  const int BT = Bsz * T;  // 4096

  __bf16* q = (__bf16*)d_ws;           // BT*D, attention output in-place
  __bf16* k = q + (size_t)BT * D;      // BT*HD
  __bf16* v = k + (size_t)BT * HD;     // BT*HD
  __bf16* at = q;

  dim3 blk(256);
  gemm_any<true, true, false><<<dim3(D / GBN, BT / GBM), blk, 0, stream>>>(x, Wq, q, BT, D, D);
  gemm_any<true, true, false><<<dim3(HD / GBN, BT / GBM), blk, 0, stream>>>(x, Wk, k, BT, HD, D);
  gemm_any<true, true, false><<<dim3(HD / GBN, BT / GBM), blk, 0, stream>>>(x, Wv, v, BT, HD, D);
  mqa_attn_kernel<<<dim3(T / TQ, H, Bsz), blk, 0, stream>>>(q, k, v, at, T);
  gemm_any<false, true, true><<<dim3(D / GBN, BT / GBM), blk, 0, stream>>>(at, Wo, out, BT, D, D);
}

// Round 4
// 1212.852 us; speedup vs baseline: 1.6442x; 1.6442x over previous
//
#include <hip/hip_runtime.h>

typedef __bf16 bf16x8 __attribute__((ext_vector_type(8)));
typedef float f32x4 __attribute__((ext_vector_type(4)));

__device__ inline __bf16 to_bf16(float f) {  // round-to-nearest-even
  union { float f; unsigned u; } x; x.f = f;
  unsigned r = (x.u + 0x7FFFu + ((x.u >> 16) & 1u)) >> 16;
  union { unsigned short s; __bf16 b; } y; y.s = (unsigned short)r;
  return y.b;
}

// ---------------------------------------------------------------------------
// GEMM C[M,N] = A[M,K] @ B[K,N], row-major. (unchanged from round 3)
// ---------------------------------------------------------------------------
#define GBM 128
#define GBN 128
#define GBK 32
#define LDSA 40
#define LDSB 40

template <bool A_F32, bool B_F32, bool C_F32>
__global__ __launch_bounds__(256, 2) void gemm_any(
    const void* __restrict__ Ap, const void* __restrict__ Bp,
    void* __restrict__ Cp, int M, int N, int K)
{
  __shared__ __align__(16) __bf16 Asl[GBM * LDSA];
  __shared__ __align__(16) __bf16 Bsl[GBN * LDSB];
  const int tid  = threadIdx.x;
  const int wave = tid >> 6, lane = tid & 63;
  const int quad = lane >> 4, l16 = lane & 15;
  const int m0 = blockIdx.y * GBM, n0 = blockIdx.x * GBN;
  const int wm = (wave >> 1) * 64, wn = (wave & 1) * 64;

  f32x4 acc[4][4];
#pragma unroll
  for (int i = 0; i < 4; i++)
#pragma unroll
    for (int j = 0; j < 4; j++) acc[i][j] = (f32x4){0.f, 0.f, 0.f, 0.f};

  for (int k0 = 0; k0 < K; k0 += GBK) {
    __syncthreads();
#pragma unroll
    for (int g = tid; g < (GBM * GBK) / 4; g += 256) {
      int row = g >> 3, seg = (g & 7) * 4;
      __bf16 h[4];
      if (A_F32) {
        float4 vv = *(const float4*)((const float*)Ap + (size_t)(m0 + row) * K + k0 + seg);
        h[0] = to_bf16(vv.x); h[1] = to_bf16(vv.y);
        h[2] = to_bf16(vv.z); h[3] = to_bf16(vv.w);
        *(uint2*)&Asl[row * LDSA + seg] = *(const uint2*)h;
      } else {
        *(uint2*)&Asl[row * LDSA + seg] =
            *(const uint2*)((const __bf16*)Ap + (size_t)(m0 + row) * K + k0 + seg);
      }
    }
#pragma unroll
    for (int g = tid; g < (GBK * GBN) / 4; g += 256) {
      int k = g >> 5, c = g & 31;
      __bf16 h[4];
      if (B_F32) {
        float4 vv = *(const float4*)((const float*)Bp + (size_t)(k0 + k) * N + n0 + c * 4);
        h[0] = to_bf16(vv.x); h[1] = to_bf16(vv.y);
        h[2] = to_bf16(vv.z); h[3] = to_bf16(vv.w);
      } else {
        *(uint2*)h = *(const uint2*)((const __bf16*)Bp + (size_t)(k0 + k) * N + n0 + c * 4);
      }
#pragma unroll
      for (int i = 0; i < 4; i++) Bsl[(c * 4 + i) * LDSB + k] = h[i];
    }
    __syncthreads();

    bf16x8 af[4], bfr[4];
#pragma unroll
    for (int i = 0; i < 4; i++)
      af[i] = *(const bf16x8*)&Asl[(wm + i * 16 + l16) * LDSA + quad * 8];
#pragma unroll
    for (int i = 0; i < 4; i++)
      bfr[i] = *(const bf16x8*)&Bsl[(wn + i * 16 + l16) * LDSB + quad * 8];
#pragma unroll
    for (int mi = 0; mi < 4; mi++)
#pragma unroll
      for (int ni = 0; ni < 4; ni++)
        acc[mi][ni] = __builtin_amdgcn_mfma_f32_16x16x32_bf16(
            af[mi], bfr[ni], acc[mi][ni], 0, 0, 0);
  }

#pragma unroll
  for (int mi = 0; mi < 4; mi++)
#pragma unroll
    for (int ni = 0; ni < 4; ni++)
#pragma unroll
      for (int r = 0; r < 4; r++) {
        int row = m0 + wm + mi * 16 + quad * 4 + r;
        int col = n0 + wn + ni * 16 + l16;
        if (C_F32) ((float*)Cp)[(size_t)row * N + col] = acc[mi][ni][r];
        else ((__bf16*)Cp)[(size_t)row * N + col] = to_bf16(acc[mi][ni][r]);
      }
}

// ---------------------------------------------------------------------------
// MQA causal flash attention, MFMA version.
// Block = 256 thr = 4 waves = 4 heads (MQA: shared K/V staged once per chunk).
// Each wave: 32 q-rows of its head. Q-frags in registers for kernel lifetime.
// Grid (64,8,1): bx -> {qtile-pair index t, batch}; by -> {head-group, flip}.
// qt = flip ? 63-t : t  => co-resident pairs (t, 63-t) have uniform causal work.
// LDS: Ks[key][d] (stride 136), VsT[d][key] rotated 8-key blocks (stride 72),
// Pr per-wave [row][key] (stride 72) for the P C-layout -> A-layout transform.
// IN-PLACE SAFE Q==O: each block touches only its own (rows x head-cols).
// ---------------------------------------------------------------------------
#define KS_LD 136
#define VT_LD 72
#define PR_LD 72

__global__ __launch_bounds__(256) void mqa_attn_mfma(
    const __bf16* Q, const __bf16* __restrict__ Km,
    const __bf16* __restrict__ Vm, __bf16* O)
{
  __shared__ __align__(16) __bf16 Ks[64 * KS_LD];
  __shared__ __align__(16) __bf16 VsT[128 * VT_LD];
  __shared__ __align__(16) __bf16 Pr[4][32 * PR_LD];

  const int tid = threadIdx.x, wave = tid >> 6, lane = tid & 63;
  const int quad = lane >> 4, l16 = lane & 15;
  const int t = blockIdx.x >> 1, bat = blockIdx.x & 1;
  const int hg = blockIdx.y & 3, flip = blockIdx.y >> 2;
  const int qt = flip ? (63 - t) : t;
  const int h = hg * 4 + wave;
  const int q0 = qt * 32;
  const size_t qgrow = (size_t)bat * 2048 + q0;
  const float SCL2 = 0.08838834764831845f * 1.4426950408889634f;  // scale*log2e

  // Q fragments: A[m=l16][k=quad*8+j], [mi][ks] covering 32 rows x 128 d.
  bf16x8 qf[2][4];
#pragma unroll
  for (int mi = 0; mi < 2; mi++)
#pragma unroll
    for (int ks = 0; ks < 4; ks++)
      qf[mi][ks] = *(const bf16x8*)(Q + (qgrow + mi * 16 + l16) * 2048 +
                                    h * 128 + ks * 32 + quad * 8);

  f32x4 oa[2][8];
#pragma unroll
  for (int mi = 0; mi < 2; mi++)
#pragma unroll
    for (int nt = 0; nt < 8; nt++) oa[mi][nt] = (f32x4){0.f, 0.f, 0.f, 0.f};
  float m2[8], l2[8];
#pragma unroll
  for (int i = 0; i < 8; i++) { m2[i] = -INFINITY; l2[i] = 0.f; }

  const __bf16* Kb = Km + (size_t)bat * 2048 * 128;
  const __bf16* Vb = Vm + (size_t)bat * 2048 * 128;
  const int qmax = q0 + 31;

  for (int sc = 0; sc <= qmax; sc += 64) {
    __syncthreads();  // prior chunk's frag reads done before restage
    // --- stage K[key][d], 16B/thread x4; clamp rows at causal edge ---
#pragma unroll
    for (int i = 0; i < 4; i++) {
      int v = tid + i * 256;
      int row = v >> 4, dseg = (v & 15) * 8;
      int kr = sc + row; if (kr > 2047) kr = 2047;
      *(bf16x8*)&Ks[row * KS_LD + dseg] =
          *(const bf16x8*)&Kb[(size_t)kr * 128 + dseg];
    }
    // --- stage V transposed [d][key], 4x4 register transpose, b64 writes,
    //     8-key-block rotation pb=(blk+(d>>2))&7 to spread banks ---
#pragma unroll
    for (int i = 0; i < 2; i++) {
      int g = tid + i * 256;          // 0..511
      int dg = (g & 31) * 4, kg = (g >> 5) * 4;
      union { uint2 u; unsigned short s[4]; } a[4], o;
#pragma unroll
      for (int i2 = 0; i2 < 4; i2++) {
        int kr = sc + kg + i2; if (kr > 2047) kr = 2047;
        a[i2].u = *(const uint2*)&Vb[(size_t)kr * 128 + dg];
      }
#pragma unroll
      for (int j = 0; j < 4; j++) {
        int d = dg + j;
        int pb = ((kg >> 3) + (d >> 2)) & 7;
        o.s[0] = a[0].s[j]; o.s[1] = a[1].s[j];
        o.s[2] = a[2].s[j]; o.s[3] = a[3].s[j];
        *(uint2*)&VsT[d * VT_LD + pb * 8 + (kg & 7)] = o.u;
      }
    }
    __syncthreads();

    // --- S = Q @ K^T : B-frag = Ks[kt*16+l16][ks*32+quad*8..+7] ---
    f32x4 sf[2][4];
#pragma unroll
    for (int mi = 0; mi < 2; mi++)
#pragma unroll
      for (int kt = 0; kt < 4; kt++) sf[mi][kt] = (f32x4){0.f, 0.f, 0.f, 0.f};
#pragma unroll
    for (int ks = 0; ks < 4; ks++)
#pragma unroll
      for (int kt = 0; kt < 4; kt++) {
        bf16x8 kf = *(const bf16x8*)&Ks[(kt * 16 + l16) * KS_LD + ks * 32 + quad * 8];
        sf[0][kt] = __builtin_amdgcn_mfma_f32_16x16x32_bf16(qf[0][ks], kf, sf[0][kt], 0, 0, 0);
        sf[1][kt] = __builtin_amdgcn_mfma_f32_16x16x32_bf16(qf[1][ks], kf, sf[1][kt], 0, 0, 0);
      }

    // --- online softmax (exp2 units). Row = q0+mi*16+quad*4+r; the 16 lanes
    //     of a quad-group share a row; shfl_xor 1..8 stays in-group. ---
    float alf[8];
#pragma unroll
    for (int mi = 0; mi < 2; mi++)
#pragma unroll
      for (int r = 0; r < 4; r++) {
        const int i = mi * 4 + r;
        const int qrow = q0 + mi * 16 + quad * 4 + r;
        float mx = -INFINITY;
#pragma unroll
        for (int kt = 0; kt < 4; kt++) {
          int key = sc + kt * 16 + l16;
          float sv = (key <= qrow) ? sf[mi][kt][r] * SCL2 : -INFINITY;
          sf[mi][kt][r] = sv;
          mx = fmaxf(mx, sv);
        }
#pragma unroll
        for (int off = 1; off < 16; off <<= 1)
          mx = fmaxf(mx, __shfl_xor(mx, off, 64));
        float mnew = fmaxf(m2[i], mx);      // key sc<=qrow always -> finite
        float al = exp2f(m2[i] - mnew);     // first chunk: exp2(-inf)=0
        m2[i] = mnew;
        float rs = 0.f;
#pragma unroll
        for (int kt = 0; kt < 4; kt++) {
          float p = exp2f(sf[mi][kt][r] - mnew);  // masked: exp2(-inf)=0
          sf[mi][kt][r] = p;
          rs += p;
        }
#pragma unroll
        for (int off = 1; off < 16; off <<= 1)
          rs += __shfl_xor(rs, off, 64);
        l2[i] = l2[i] * al + rs;
        alf[i] = al;
      }
    // rescale O accumulator
#pragma unroll
    for (int mi = 0; mi < 2; mi++)
#pragma unroll
      for (int nt = 0; nt < 8; nt++)
#pragma unroll
        for (int r = 0; r < 4; r++) oa[mi][nt][r] *= alf[mi * 4 + r];

    // --- P: C-layout regs -> per-wave LDS [row][key] (bf16) ---
    __bf16* prw = Pr[wave];
#pragma unroll
    for (int mi = 0; mi < 2; mi++)
#pragma unroll
      for (int kt = 0; kt < 4; kt++)
#pragma unroll
        for (int r = 0; r < 4; r++)
          prw[(mi * 16 + quad * 4 + r) * PR_LD + kt * 16 + l16] =
              to_bf16(sf[mi][kt][r]);

    // --- O += P @ V : A-frag from Pr (b128), B-frag from rotated VsT ---
#pragma unroll
    for (int ks2 = 0; ks2 < 2; ks2++) {
      bf16x8 pf0 = *(const bf16x8*)&prw[(l16) * PR_LD + ks2 * 32 + quad * 8];
      bf16x8 pf1 = *(const bf16x8*)&prw[(16 + l16) * PR_LD + ks2 * 32 + quad * 8];
#pragma unroll
      for (int nt = 0; nt < 8; nt++) {
        int d = nt * 16 + l16;
        int pb = ((ks2 * 4 + quad) + (d >> 2)) & 7;
        bf16x8 vf = *(const bf16x8*)&VsT[d * VT_LD + pb * 8];
        oa[0][nt] = __builtin_amdgcn_mfma_f32_16x16x32_bf16(pf0, vf, oa[0][nt], 0, 0, 0);
        oa[1][nt] = __builtin_amdgcn_mfma_f32_16x16x32_bf16(pf1, vf, oa[1][nt], 0, 0, 0);
      }
    }
  }

  // epilogue: O[row][h*128+d] = oa/l
#pragma unroll
  for (int mi = 0; mi < 2; mi++)
#pragma unroll
    for (int r = 0; r < 4; r++) {
      float inv = 1.f / l2[mi * 4 + r];   // l>0: diagonal key unmasked
      size_t row = qgrow + mi * 16 + quad * 4 + r;
#pragma unroll
      for (int nt = 0; nt < 8; nt++)
        O[row * 2048 + h * 128 + nt * 16 + l16] = to_bf16(oa[mi][nt][r] * inv);
    }
}

// ---------------------------------------------------------------------------
// fp32 I/O, bf16 internals.
// ws (bf16 elems): q/at[BT*D] | k[BT*HD] | v[BT*HD] = 18.9 MB
// ---------------------------------------------------------------------------
extern "C" void kernel_launch(void* const* d_in, const int* in_sizes, int n_in,
                              void* d_out, int out_size, void* d_ws, size_t ws_size,
                              hipStream_t stream) {
  const float* x  = (const float*)d_in[0];
  const float* Wq = (const float*)d_in[1];
  const float* Wk = (const float*)d_in[2];
  const float* Wv = (const float*)d_in[3];
  const float* Wo = (const float*)d_in[4];
  float* out = (float*)d_out;

  const int Bsz = 2, T = 2048, D = 2048, HD = 128;
  const int BT = Bsz * T;  // 4096

  __bf16* q = (__bf16*)d_ws;           // BT*D, attention output in-place
  __bf16* k = q + (size_t)BT * D;      // BT*HD
  __bf16* v = k + (size_t)BT * HD;     // BT*HD
  __bf16* at = q;

  dim3 blk(256);
  gemm_any<true, true, false><<<dim3(D / GBN, BT / GBM), blk, 0, stream>>>(x, Wq, q, BT, D, D);
  gemm_any<true, true, false><<<dim3(HD / GBN, BT / GBM), blk, 0, stream>>>(x, Wk, k, BT, HD, D);
  gemm_any<true, true, false><<<dim3(HD / GBN, BT / GBM), blk, 0, stream>>>(x, Wv, v, BT, HD, D);
  mqa_attn_mfma<<<dim3(64, 8, 1), blk, 0, stream>>>(q, k, v, at);
  gemm_any<false, true, true><<<dim3(D / GBN, BT / GBM), blk, 0, stream>>>(at, Wo, out, BT, D, D);
}

// Round 5
// 497.600 us; speedup vs baseline: 4.0077x; 2.4374x over previous
//
#include <hip/hip_runtime.h>

typedef __bf16 bf16x8 __attribute__((ext_vector_type(8)));
typedef float f32x4 __attribute__((ext_vector_type(4)));

__device__ inline __bf16 to_bf16(float f) {  // RNE (kept for attention path)
  union { float f; unsigned u; } x; x.f = f;
  unsigned r = (x.u + 0x7FFFu + ((x.u >> 16) & 1u)) >> 16;
  union { unsigned short s; __bf16 b; } y; y.s = (unsigned short)r;
  return y.b;
}

// Async global->LDS, 16B per lane. LDS dest is wave-uniform base + lane*16.
__device__ inline void gload16(const __bf16* g, __bf16* l) {
  __builtin_amdgcn_global_load_lds(
      (const __attribute__((address_space(1))) unsigned int*)g,
      (__attribute__((address_space(3))) unsigned int*)l, 16, 0, 0);
}

// ---------------------------------------------------------------------------
// Prep: fp32 -> bf16 elementwise (x). 8 elems/thread.
// ---------------------------------------------------------------------------
__global__ __launch_bounds__(256) void conv_bf16(
    const float* __restrict__ in, __bf16* __restrict__ out)
{
  size_t i = ((size_t)blockIdx.x * 256 + threadIdx.x) * 8;
  float4 a = *(const float4*)&in[i];
  float4 b = *(const float4*)&in[i + 4];
  bf16x8 h;
  h[0] = (__bf16)a.x; h[1] = (__bf16)a.y; h[2] = (__bf16)a.z; h[3] = (__bf16)a.w;
  h[4] = (__bf16)b.x; h[5] = (__bf16)b.y; h[6] = (__bf16)b.z; h[7] = (__bf16)b.w;
  *(bf16x8*)&out[i] = h;
}

// ---------------------------------------------------------------------------
// Prep: W fp32 [Kd][Nd] -> WT bf16 [Nd][Kd]. 64x64 LDS tile.
// ---------------------------------------------------------------------------
__global__ __launch_bounds__(256) void transpose_w(
    const float* __restrict__ W, __bf16* __restrict__ WT, int Kd, int Nd)
{
  __shared__ __bf16 Ts[64 * 72];
  const int tid = threadIdx.x;
  const int c0 = blockIdx.x * 64, r0 = blockIdx.y * 64;
#pragma unroll
  for (int i = 0; i < 4; i++) {
    int row = (tid >> 4) + i * 16, cv = (tid & 15) * 4;
    float4 w = *(const float4*)&W[(size_t)(r0 + row) * Nd + c0 + cv];
    Ts[(cv + 0) * 72 + row] = (__bf16)w.x;
    Ts[(cv + 1) * 72 + row] = (__bf16)w.y;
    Ts[(cv + 2) * 72 + row] = (__bf16)w.z;
    Ts[(cv + 3) * 72 + row] = (__bf16)w.w;
  }
  __syncthreads();
#pragma unroll
  for (int i = 0; i < 4; i++) {
    int n = (tid >> 4) + i * 16, kseg = (tid & 15) * 4;
    *(uint2*)&WT[(size_t)(c0 + n) * Kd + r0 + kseg] = *(uint2*)&Ts[n * 72 + kseg];
  }
}

// ---------------------------------------------------------------------------
// Fused q/k/v projection GEMM (pure bf16, m97 structure).
// C = A[4096,2048] @ BT^T.  n-block 0..15 -> WqT/q, 16 -> WkT/k, 17 -> WvT/v.
// LDS [row][32] contiguous (global_load_lds lane order), b128 frag reads.
// Frag layouts (verified rounds 3-4): A lane=A[m=l16][k=quad*8+j],
// B lane=BT[n=l16][k=quad*8+j], D reg r = D[row=quad*4+r][col=l16].
// ---------------------------------------------------------------------------
__global__ __launch_bounds__(256) void gemm_qkv(
    const __bf16* __restrict__ A, const __bf16* __restrict__ WqT,
    const __bf16* __restrict__ WkT, const __bf16* __restrict__ WvT,
    __bf16* __restrict__ Cq, __bf16* __restrict__ Ck, __bf16* __restrict__ Cv)
{
  __shared__ __align__(16) __bf16 Asl[128 * 32];
  __shared__ __align__(16) __bf16 Bsl[128 * 32];
  const int tid = threadIdx.x, wave = tid >> 6, lane = tid & 63;
  const int quad = lane >> 4, l16 = lane & 15;
  const int nb = blockIdx.x, m0 = blockIdx.y * 128;
  const __bf16* BT; __bf16* C; int ldC, c0;
  if (nb < 16)       { BT = WqT + (size_t)nb * 128 * 2048; C = Cq; ldC = 2048; c0 = nb * 128; }
  else if (nb == 16) { BT = WkT; C = Ck; ldC = 128; c0 = 0; }
  else               { BT = WvT; C = Cv; ldC = 128; c0 = 0; }
  const int wm = (wave >> 1) * 64, wn = (wave & 1) * 64;
  const int lrow = lane >> 2, lseg = (lane & 3) * 8;

  f32x4 acc[4][4];
#pragma unroll
  for (int i = 0; i < 4; i++)
#pragma unroll
    for (int j = 0; j < 4; j++) acc[i][j] = (f32x4){0.f, 0.f, 0.f, 0.f};

  for (int k0 = 0; k0 < 2048; k0 += 32) {
    __syncthreads();
#pragma unroll
    for (int c = 0; c < 2; c++) {
      int ch = wave * 2 + c;  // rows [ch*16, ch*16+16)
      gload16(&A[(size_t)(m0 + ch * 16 + lrow) * 2048 + k0 + lseg], &Asl[ch * 512]);
      gload16(&BT[(size_t)(ch * 16 + lrow) * 2048 + k0 + lseg], &Bsl[ch * 512]);
    }
    __syncthreads();

    bf16x8 af[4], bf[4];
#pragma unroll
    for (int i = 0; i < 4; i++)
      af[i] = *(const bf16x8*)&Asl[(wm + i * 16 + l16) * 32 + quad * 8];
#pragma unroll
    for (int i = 0; i < 4; i++)
      bf[i] = *(const bf16x8*)&Bsl[(wn + i * 16 + l16) * 32 + quad * 8];
#pragma unroll
    for (int mi = 0; mi < 4; mi++)
#pragma unroll
      for (int ni = 0; ni < 4; ni++)
        acc[mi][ni] = __builtin_amdgcn_mfma_f32_16x16x32_bf16(
            af[mi], bf[ni], acc[mi][ni], 0, 0, 0);
  }

#pragma unroll
  for (int mi = 0; mi < 4; mi++)
#pragma unroll
    for (int ni = 0; ni < 4; ni++)
#pragma unroll
      for (int r = 0; r < 4; r++) {
        int row = m0 + wm + mi * 16 + quad * 4 + r;
        int col = c0 + wn + ni * 16 + l16;
        C[(size_t)row * ldC + col] = (__bf16)acc[mi][ni][r];
      }
}

// ---------------------------------------------------------------------------
// Final GEMM: out[4096,2048] fp32 = at[4096,2048] bf16 @ Wo[2048,2048] fp32.
// A via global_load_lds; B converted+transposed in staging into swizzled
// BsT[n][k]: elem addr = n*32 + pb*8 + (k&7), pb = ((k>>3)+(n>>2))&3.
// Frag read is b128, 2-way max; writes are 4x b64, <=8-way.
// ---------------------------------------------------------------------------
__global__ __launch_bounds__(256) void gemm_out(
    const __bf16* __restrict__ A, const float* __restrict__ B,
    float* __restrict__ Cp)
{
  __shared__ __align__(16) __bf16 Asl[128 * 32];
  __shared__ __align__(16) __bf16 BsT[128 * 32];
  const int tid = threadIdx.x, wave = tid >> 6, lane = tid & 63;
  const int quad = lane >> 4, l16 = lane & 15;
  const int n0 = blockIdx.x * 128, m0 = blockIdx.y * 128;
  const int wm = (wave >> 1) * 64, wn = (wave & 1) * 64;
  const int lrow = lane >> 2, lseg = (lane & 3) * 8;
  const int kg = (tid >> 5) * 4, ng = (tid & 31) * 4;

  f32x4 acc[4][4];
#pragma unroll
  for (int i = 0; i < 4; i++)
#pragma unroll
    for (int j = 0; j < 4; j++) acc[i][j] = (f32x4){0.f, 0.f, 0.f, 0.f};

  for (int k0 = 0; k0 < 2048; k0 += 32) {
    __syncthreads();
#pragma unroll
    for (int c = 0; c < 2; c++) {
      int ch = wave * 2 + c;
      gload16(&A[(size_t)(m0 + ch * 16 + lrow) * 2048 + k0 + lseg], &Asl[ch * 512]);
    }
    // B tile: 4 k-rows x 4 n-cols per thread, register transpose, swizzled b64.
    __bf16 h[4][4];
#pragma unroll
    for (int i = 0; i < 4; i++) {
      float4 w = *(const float4*)&B[(size_t)(k0 + kg + i) * 2048 + n0 + ng];
      h[i][0] = (__bf16)w.x; h[i][1] = (__bf16)w.y;
      h[i][2] = (__bf16)w.z; h[i][3] = (__bf16)w.w;
    }
#pragma unroll
    for (int j = 0; j < 4; j++) {
      int n = ng + j;
      int pb = ((kg >> 3) + (n >> 2)) & 3;
      __bf16 o4[4] = {h[0][j], h[1][j], h[2][j], h[3][j]};
      *(uint2*)&BsT[n * 32 + pb * 8 + (kg & 7)] = *(uint2*)o4;
    }
    __syncthreads();

    bf16x8 af[4], bf[4];
#pragma unroll
    for (int i = 0; i < 4; i++)
      af[i] = *(const bf16x8*)&Asl[(wm + i * 16 + l16) * 32 + quad * 8];
#pragma unroll
    for (int i = 0; i < 4; i++) {
      int n = wn + i * 16 + l16;
      int pb = (quad + (n >> 2)) & 3;
      bf[i] = *(const bf16x8*)&BsT[n * 32 + pb * 8];
    }
#pragma unroll
    for (int mi = 0; mi < 4; mi++)
#pragma unroll
      for (int ni = 0; ni < 4; ni++)
        acc[mi][ni] = __builtin_amdgcn_mfma_f32_16x16x32_bf16(
            af[mi], bf[ni], acc[mi][ni], 0, 0, 0);
  }

#pragma unroll
  for (int mi = 0; mi < 4; mi++)
#pragma unroll
    for (int ni = 0; ni < 4; ni++)
#pragma unroll
      for (int r = 0; r < 4; r++) {
        int row = m0 + wm + mi * 16 + quad * 4 + r;
        int col = n0 + wn + ni * 16 + l16;
        Cp[(size_t)row * 2048 + col] = acc[mi][ni][r];
      }
}

// ---------------------------------------------------------------------------
// MQA causal flash attention (MFMA) — unchanged from round 4 (passing).
// ---------------------------------------------------------------------------
#define KS_LD 136
#define VT_LD 72
#define PR_LD 72

__global__ __launch_bounds__(256) void mqa_attn_mfma(
    const __bf16* Q, const __bf16* __restrict__ Km,
    const __bf16* __restrict__ Vm, __bf16* O)
{
  __shared__ __align__(16) __bf16 Ks[64 * KS_LD];
  __shared__ __align__(16) __bf16 VsT[128 * VT_LD];
  __shared__ __align__(16) __bf16 Pr[4][32 * PR_LD];

  const int tid = threadIdx.x, wave = tid >> 6, lane = tid & 63;
  const int quad = lane >> 4, l16 = lane & 15;
  const int t = blockIdx.x >> 1, bat = blockIdx.x & 1;
  const int hg = blockIdx.y & 3, flip = blockIdx.y >> 2;
  const int qt = flip ? (63 - t) : t;
  const int h = hg * 4 + wave;
  const int q0 = qt * 32;
  const size_t qgrow = (size_t)bat * 2048 + q0;
  const float SCL2 = 0.08838834764831845f * 1.4426950408889634f;

  bf16x8 qf[2][4];
#pragma unroll
  for (int mi = 0; mi < 2; mi++)
#pragma unroll
    for (int ks = 0; ks < 4; ks++)
      qf[mi][ks] = *(const bf16x8*)(Q + (qgrow + mi * 16 + l16) * 2048 +
                                    h * 128 + ks * 32 + quad * 8);

  f32x4 oa[2][8];
#pragma unroll
  for (int mi = 0; mi < 2; mi++)
#pragma unroll
    for (int nt = 0; nt < 8; nt++) oa[mi][nt] = (f32x4){0.f, 0.f, 0.f, 0.f};
  float m2[8], l2[8];
#pragma unroll
  for (int i = 0; i < 8; i++) { m2[i] = -INFINITY; l2[i] = 0.f; }

  const __bf16* Kb = Km + (size_t)bat * 2048 * 128;
  const __bf16* Vb = Vm + (size_t)bat * 2048 * 128;
  const int qmax = q0 + 31;

  for (int sc = 0; sc <= qmax; sc += 64) {
    __syncthreads();
#pragma unroll
    for (int i = 0; i < 4; i++) {
      int v = tid + i * 256;
      int row = v >> 4, dseg = (v & 15) * 8;
      int kr = sc + row; if (kr > 2047) kr = 2047;
      *(bf16x8*)&Ks[row * KS_LD + dseg] =
          *(const bf16x8*)&Kb[(size_t)kr * 128 + dseg];
    }
#pragma unroll
    for (int i = 0; i < 2; i++) {
      int g = tid + i * 256;
      int dg = (g & 31) * 4, kg2 = (g >> 5) * 4;
      union { uint2 u; unsigned short s[4]; } a[4], o;
#pragma unroll
      for (int i2 = 0; i2 < 4; i2++) {
        int kr = sc + kg2 + i2; if (kr > 2047) kr = 2047;
        a[i2].u = *(const uint2*)&Vb[(size_t)kr * 128 + dg];
      }
#pragma unroll
      for (int j = 0; j < 4; j++) {
        int d = dg + j;
        int pb = ((kg2 >> 3) + (d >> 2)) & 7;
        o.s[0] = a[0].s[j]; o.s[1] = a[1].s[j];
        o.s[2] = a[2].s[j]; o.s[3] = a[3].s[j];
        *(uint2*)&VsT[d * VT_LD + pb * 8 + (kg2 & 7)] = o.u;
      }
    }
    __syncthreads();

    f32x4 sf[2][4];
#pragma unroll
    for (int mi = 0; mi < 2; mi++)
#pragma unroll
      for (int kt = 0; kt < 4; kt++) sf[mi][kt] = (f32x4){0.f, 0.f, 0.f, 0.f};
#pragma unroll
    for (int ks = 0; ks < 4; ks++)
#pragma unroll
      for (int kt = 0; kt < 4; kt++) {
        bf16x8 kf = *(const bf16x8*)&Ks[(kt * 16 + l16) * KS_LD + ks * 32 + quad * 8];
        sf[0][kt] = __builtin_amdgcn_mfma_f32_16x16x32_bf16(qf[0][ks], kf, sf[0][kt], 0, 0, 0);
        sf[1][kt] = __builtin_amdgcn_mfma_f32_16x16x32_bf16(qf[1][ks], kf, sf[1][kt], 0, 0, 0);
      }

    float alf[8];
#pragma unroll
    for (int mi = 0; mi < 2; mi++)
#pragma unroll
      for (int r = 0; r < 4; r++) {
        const int i = mi * 4 + r;
        const int qrow = q0 + mi * 16 + quad * 4 + r;
        float mx = -INFINITY;
#pragma unroll
        for (int kt = 0; kt < 4; kt++) {
          int key = sc + kt * 16 + l16;
          float sv = (key <= qrow) ? sf[mi][kt][r] * SCL2 : -INFINITY;
          sf[mi][kt][r] = sv;
          mx = fmaxf(mx, sv);
        }
#pragma unroll
        for (int off = 1; off < 16; off <<= 1)
          mx = fmaxf(mx, __shfl_xor(mx, off, 64));
        float mnew = fmaxf(m2[i], mx);
        float al = exp2f(m2[i] - mnew);
        m2[i] = mnew;
        float rs = 0.f;
#pragma unroll
        for (int kt = 0; kt < 4; kt++) {
          float p = exp2f(sf[mi][kt][r] - mnew);
          sf[mi][kt][r] = p;
          rs += p;
        }
#pragma unroll
        for (int off = 1; off < 16; off <<= 1)
          rs += __shfl_xor(rs, off, 64);
        l2[i] = l2[i] * al + rs;
        alf[i] = al;
      }
#pragma unroll
    for (int mi = 0; mi < 2; mi++)
#pragma unroll
      for (int nt = 0; nt < 8; nt++)
#pragma unroll
        for (int r = 0; r < 4; r++) oa[mi][nt][r] *= alf[mi * 4 + r];

    __bf16* prw = Pr[wave];
#pragma unroll
    for (int mi = 0; mi < 2; mi++)
#pragma unroll
      for (int kt = 0; kt < 4; kt++)
#pragma unroll
        for (int r = 0; r < 4; r++)
          prw[(mi * 16 + quad * 4 + r) * PR_LD + kt * 16 + l16] =
              to_bf16(sf[mi][kt][r]);

#pragma unroll
    for (int ks2 = 0; ks2 < 2; ks2++) {
      bf16x8 pf0 = *(const bf16x8*)&prw[(l16) * PR_LD + ks2 * 32 + quad * 8];
      bf16x8 pf1 = *(const bf16x8*)&prw[(16 + l16) * PR_LD + ks2 * 32 + quad * 8];
#pragma unroll
      for (int nt = 0; nt < 8; nt++) {
        int d = nt * 16 + l16;
        int pb = ((ks2 * 4 + quad) + (d >> 2)) & 7;
        bf16x8 vf = *(const bf16x8*)&VsT[d * VT_LD + pb * 8];
        oa[0][nt] = __builtin_amdgcn_mfma_f32_16x16x32_bf16(pf0, vf, oa[0][nt], 0, 0, 0);
        oa[1][nt] = __builtin_amdgcn_mfma_f32_16x16x32_bf16(pf1, vf, oa[1][nt], 0, 0, 0);
      }
    }
  }

#pragma unroll
  for (int mi = 0; mi < 2; mi++)
#pragma unroll
    for (int r = 0; r < 4; r++) {
      float inv = 1.f / l2[mi * 4 + r];
      size_t row = qgrow + mi * 16 + quad * 4 + r;
#pragma unroll
      for (int nt = 0; nt < 8; nt++)
        O[row * 2048 + h * 128 + nt * 16 + l16] = to_bf16(oa[mi][nt][r] * inv);
    }
}

// ---------------------------------------------------------------------------
// Memory plan:
//   ws   : q / at (in-place)            16.78 MB   (proven ws >= 18.9 MB)
//   d_out: xb | WqT | WkT | WvT | k | v 28.3 MB    (dead before final GEMM)
// ---------------------------------------------------------------------------
extern "C" void kernel_launch(void* const* d_in, const int* in_sizes, int n_in,
                              void* d_out, int out_size, void* d_ws, size_t ws_size,
                              hipStream_t stream) {
  const float* x  = (const float*)d_in[0];
  const float* Wq = (const float*)d_in[1];
  const float* Wk = (const float*)d_in[2];
  const float* Wv = (const float*)d_in[3];
  const float* Wo = (const float*)d_in[4];
  float* out = (float*)d_out;

  __bf16* q   = (__bf16*)d_ws;                       // 8M elems, at in-place
  char* ob = (char*)d_out;
  __bf16* xb  = (__bf16*)(ob);                       // 8M elems
  __bf16* WqT = (__bf16*)(ob + 16777216);            // 4M elems
  __bf16* WkT = (__bf16*)(ob + 25165824);            // 256K
  __bf16* WvT = (__bf16*)(ob + 25690112);            // 256K
  __bf16* kb  = (__bf16*)(ob + 26214400);            // 512K
  __bf16* vb  = (__bf16*)(ob + 27262976);            // 512K

  dim3 blk(256);
  conv_bf16<<<4096, blk, 0, stream>>>(x, xb);
  transpose_w<<<dim3(32, 32), blk, 0, stream>>>(Wq, WqT, 2048, 2048);
  transpose_w<<<dim3(2, 32), blk, 0, stream>>>(Wk, WkT, 2048, 128);
  transpose_w<<<dim3(2, 32), blk, 0, stream>>>(Wv, WvT, 2048, 128);
  gemm_qkv<<<dim3(18, 32), blk, 0, stream>>>(xb, WqT, WkT, WvT, q, kb, vb);
  mqa_attn_mfma<<<dim3(64, 8, 1), blk, 0, stream>>>(q, kb, vb, q);
  gemm_out<<<dim3(16, 32), blk, 0, stream>>>(q, Wo, out);
}

// Round 7
// 379.359 us; speedup vs baseline: 5.2568x; 1.3117x over previous
//
#include <hip/hip_runtime.h>

typedef __bf16 bf16x8 __attribute__((ext_vector_type(8)));
typedef float f32x4 __attribute__((ext_vector_type(4)));

// Async global->LDS, 16B per lane. LDS dest is wave-uniform base + lane*16.
__device__ inline void gload16(const __bf16* g, __bf16* l) {
  __builtin_amdgcn_global_load_lds(
      (const __attribute__((address_space(1))) unsigned int*)g,
      (__attribute__((address_space(3))) unsigned int*)l, 16, 0, 0);
}

// ---------------------------------------------------------------------------
// Prep: fp32 -> bf16 elementwise (x). 8 elems/thread.
// ---------------------------------------------------------------------------
__global__ __launch_bounds__(256) void conv_bf16(
    const float* __restrict__ in, __bf16* __restrict__ out)
{
  size_t i = ((size_t)blockIdx.x * 256 + threadIdx.x) * 8;
  float4 a = *(const float4*)&in[i];
  float4 b = *(const float4*)&in[i + 4];
  bf16x8 h;
  h[0] = (__bf16)a.x; h[1] = (__bf16)a.y; h[2] = (__bf16)a.z; h[3] = (__bf16)a.w;
  h[4] = (__bf16)b.x; h[5] = (__bf16)b.y; h[6] = (__bf16)b.z; h[7] = (__bf16)b.w;
  *(bf16x8*)&out[i] = h;
}

// ---------------------------------------------------------------------------
// Prep: W fp32 [Kd][Nd] -> WT bf16 [Nd][Kd]. 64x64 LDS tile.
// ---------------------------------------------------------------------------
__global__ __launch_bounds__(256) void transpose_w(
    const float* __restrict__ W, __bf16* __restrict__ WT, int Kd, int Nd)
{
  __shared__ __bf16 Ts[64 * 72];
  const int tid = threadIdx.x;
  const int c0 = blockIdx.x * 64, r0 = blockIdx.y * 64;
#pragma unroll
  for (int i = 0; i < 4; i++) {
    int row = (tid >> 4) + i * 16, cv = (tid & 15) * 4;
    float4 w = *(const float4*)&W[(size_t)(r0 + row) * Nd + c0 + cv];
    Ts[(cv + 0) * 72 + row] = (__bf16)w.x;
    Ts[(cv + 1) * 72 + row] = (__bf16)w.y;
    Ts[(cv + 2) * 72 + row] = (__bf16)w.z;
    Ts[(cv + 3) * 72 + row] = (__bf16)w.w;
  }
  __syncthreads();
#pragma unroll
  for (int i = 0; i < 4; i++) {
    int n = (tid >> 4) + i * 16, kseg = (tid & 15) * 4;
    *(uint2*)&WT[(size_t)(c0 + n) * Kd + r0 + kseg] = *(uint2*)&Ts[n * 72 + kseg];
  }
}

// ---------------------------------------------------------------------------
// Fused q/k/v projection GEMM (pure bf16, m97 structure). Unchanged.
// ---------------------------------------------------------------------------
__global__ __launch_bounds__(256) void gemm_qkv(
    const __bf16* __restrict__ A, const __bf16* __restrict__ WqT,
    const __bf16* __restrict__ WkT, const __bf16* __restrict__ WvT,
    __bf16* __restrict__ Cq, __bf16* __restrict__ Ck, __bf16* __restrict__ Cv)
{
  __shared__ __align__(16) __bf16 Asl[128 * 32];
  __shared__ __align__(16) __bf16 Bsl[128 * 32];
  const int tid = threadIdx.x, wave = tid >> 6, lane = tid & 63;
  const int quad = lane >> 4, l16 = lane & 15;
  const int nb = blockIdx.x, m0 = blockIdx.y * 128;
  const __bf16* BT; __bf16* C; int ldC, c0;
  if (nb < 16)       { BT = WqT + (size_t)nb * 128 * 2048; C = Cq; ldC = 2048; c0 = nb * 128; }
  else if (nb == 16) { BT = WkT; C = Ck; ldC = 128; c0 = 0; }
  else               { BT = WvT; C = Cv; ldC = 128; c0 = 0; }
  const int wm = (wave >> 1) * 64, wn = (wave & 1) * 64;
  const int lrow = lane >> 2, lseg = (lane & 3) * 8;

  f32x4 acc[4][4];
#pragma unroll
  for (int i = 0; i < 4; i++)
#pragma unroll
    for (int j = 0; j < 4; j++) acc[i][j] = (f32x4){0.f, 0.f, 0.f, 0.f};

  for (int k0 = 0; k0 < 2048; k0 += 32) {
    __syncthreads();
#pragma unroll
    for (int c = 0; c < 2; c++) {
      int ch = wave * 2 + c;
      gload16(&A[(size_t)(m0 + ch * 16 + lrow) * 2048 + k0 + lseg], &Asl[ch * 512]);
      gload16(&BT[(size_t)(ch * 16 + lrow) * 2048 + k0 + lseg], &Bsl[ch * 512]);
    }
    __syncthreads();

    bf16x8 af[4], bf[4];
#pragma unroll
    for (int i = 0; i < 4; i++)
      af[i] = *(const bf16x8*)&Asl[(wm + i * 16 + l16) * 32 + quad * 8];
#pragma unroll
    for (int i = 0; i < 4; i++)
      bf[i] = *(const bf16x8*)&Bsl[(wn + i * 16 + l16) * 32 + quad * 8];
#pragma unroll
    for (int mi = 0; mi < 4; mi++)
#pragma unroll
      for (int ni = 0; ni < 4; ni++)
        acc[mi][ni] = __builtin_amdgcn_mfma_f32_16x16x32_bf16(
            af[mi], bf[ni], acc[mi][ni], 0, 0, 0);
  }

#pragma unroll
  for (int mi = 0; mi < 4; mi++)
#pragma unroll
    for (int ni = 0; ni < 4; ni++)
#pragma unroll
      for (int r = 0; r < 4; r++) {
        int row = m0 + wm + mi * 16 + quad * 4 + r;
        int col = c0 + wn + ni * 16 + l16;
        C[(size_t)row * ldC + col] = (__bf16)acc[mi][ni][r];
      }
}

// ---------------------------------------------------------------------------
// Final GEMM: out fp32 = at bf16 @ Wo fp32. Unchanged.
// ---------------------------------------------------------------------------
__global__ __launch_bounds__(256) void gemm_out(
    const __bf16* __restrict__ A, const float* __restrict__ B,
    float* __restrict__ Cp)
{
  __shared__ __align__(16) __bf16 Asl[128 * 32];
  __shared__ __align__(16) __bf16 BsT[128 * 32];
  const int tid = threadIdx.x, wave = tid >> 6, lane = tid & 63;
  const int quad = lane >> 4, l16 = lane & 15;
  const int n0 = blockIdx.x * 128, m0 = blockIdx.y * 128;
  const int wm = (wave >> 1) * 64, wn = (wave & 1) * 64;
  const int lrow = lane >> 2, lseg = (lane & 3) * 8;
  const int kg = (tid >> 5) * 4, ng = (tid & 31) * 4;

  f32x4 acc[4][4];
#pragma unroll
  for (int i = 0; i < 4; i++)
#pragma unroll
    for (int j = 0; j < 4; j++) acc[i][j] = (f32x4){0.f, 0.f, 0.f, 0.f};

  for (int k0 = 0; k0 < 2048; k0 += 32) {
    __syncthreads();
#pragma unroll
    for (int c = 0; c < 2; c++) {
      int ch = wave * 2 + c;
      gload16(&A[(size_t)(m0 + ch * 16 + lrow) * 2048 + k0 + lseg], &Asl[ch * 512]);
    }
    __bf16 h[4][4];
#pragma unroll
    for (int i = 0; i < 4; i++) {
      float4 w = *(const float4*)&B[(size_t)(k0 + kg + i) * 2048 + n0 + ng];
      h[i][0] = (__bf16)w.x; h[i][1] = (__bf16)w.y;
      h[i][2] = (__bf16)w.z; h[i][3] = (__bf16)w.w;
    }
#pragma unroll
    for (int j = 0; j < 4; j++) {
      int n = ng + j;
      int pb = ((kg >> 3) + (n >> 2)) & 3;
      __bf16 o4[4] = {h[0][j], h[1][j], h[2][j], h[3][j]};
      *(uint2*)&BsT[n * 32 + pb * 8 + (kg & 7)] = *(uint2*)o4;
    }
    __syncthreads();

    bf16x8 af[4], bf[4];
#pragma unroll
    for (int i = 0; i < 4; i++)
      af[i] = *(const bf16x8*)&Asl[(wm + i * 16 + l16) * 32 + quad * 8];
#pragma unroll
    for (int i = 0; i < 4; i++) {
      int n = wn + i * 16 + l16;
      int pb = (quad + (n >> 2)) & 3;
      bf[i] = *(const bf16x8*)&BsT[n * 32 + pb * 8];
    }
#pragma unroll
    for (int mi = 0; mi < 4; mi++)
#pragma unroll
      for (int ni = 0; ni < 4; ni++)
        acc[mi][ni] = __builtin_amdgcn_mfma_f32_16x16x32_bf16(
            af[mi], bf[ni], acc[mi][ni], 0, 0, 0);
  }

#pragma unroll
  for (int mi = 0; mi < 4; mi++)
#pragma unroll
    for (int ni = 0; ni < 4; ni++)
#pragma unroll
      for (int r = 0; r < 4; r++) {
        int row = m0 + wm + mi * 16 + quad * 4 + r;
        int col = n0 + wn + ni * 16 + l16;
        Cp[(size_t)row * 2048 + col] = acc[mi][ni][r];
      }
}

// ---------------------------------------------------------------------------
// MQA causal flash attention, MFMA, fixed-base streaming softmax (no max
// subtraction: scaled scores are O(1), exp2 cannot overflow; the shift
// cancels exactly in O/l). No cross-lane reductions: l = P @ ones via MFMA.
// PR_LD must be >= 64 (64 keys/chunk) and a multiple of 8 (16B-aligned rows
// for ds_read_b128) — 44 in round 6 corrupted P and NaN'd. 72 is proven.
// Block = 4 waves = 4 heads x 32 q-rows. IN-PLACE SAFE Q==O.
// ---------------------------------------------------------------------------
#define KS_LD 136
#define VT_LD 72
#define PR_LD 72

__global__ __launch_bounds__(256) void mqa_attn_mfma(
    const __bf16* Q, const __bf16* __restrict__ Km,
    const __bf16* __restrict__ Vm, __bf16* O)
{
  __shared__ __align__(16) __bf16 Ks[64 * KS_LD];
  __shared__ __align__(16) __bf16 VsT[128 * VT_LD];
  __shared__ __align__(16) __bf16 Pr[4][32 * PR_LD];

  const int tid = threadIdx.x, wave = tid >> 6, lane = tid & 63;
  const int quad = lane >> 4, l16 = lane & 15;
  const int t = blockIdx.x >> 1, bat = blockIdx.x & 1;
  const int hg = blockIdx.y & 3, flip = blockIdx.y >> 2;
  const int qt = flip ? (63 - t) : t;
  const int h = hg * 4 + wave;
  const int q0 = qt * 32;
  const size_t qgrow = (size_t)bat * 2048 + q0;
  const float SCL2 = 0.08838834764831845f * 1.4426950408889634f;  // scale*log2e

  bf16x8 qf[2][4];
#pragma unroll
  for (int mi = 0; mi < 2; mi++)
#pragma unroll
    for (int ks = 0; ks < 4; ks++)
      qf[mi][ks] = *(const bf16x8*)(Q + (qgrow + mi * 16 + l16) * 2048 +
                                    h * 128 + ks * 32 + quad * 8);

  bf16x8 ones;
#pragma unroll
  for (int i = 0; i < 8; i++) ones[i] = (__bf16)1.0f;

  f32x4 oa[2][8];
#pragma unroll
  for (int mi = 0; mi < 2; mi++)
#pragma unroll
    for (int nt = 0; nt < 8; nt++) oa[mi][nt] = (f32x4){0.f, 0.f, 0.f, 0.f};
  f32x4 lacc[2];
  lacc[0] = (f32x4){0.f, 0.f, 0.f, 0.f};
  lacc[1] = (f32x4){0.f, 0.f, 0.f, 0.f};

  const __bf16* Kb = Km + (size_t)bat * 2048 * 128;
  const __bf16* Vb = Vm + (size_t)bat * 2048 * 128;
  const int qmax = q0 + 31;

  for (int sc = 0; sc <= qmax; sc += 64) {
    __syncthreads();
    // --- stage K[key][d] ---
#pragma unroll
    for (int i = 0; i < 4; i++) {
      int v = tid + i * 256;
      int row = v >> 4, dseg = (v & 15) * 8;
      int kr = sc + row; if (kr > 2047) kr = 2047;
      *(bf16x8*)&Ks[row * KS_LD + dseg] =
          *(const bf16x8*)&Kb[(size_t)kr * 128 + dseg];
    }
    // --- stage V transposed [d][key], rotated 8-key blocks ---
#pragma unroll
    for (int i = 0; i < 2; i++) {
      int g = tid + i * 256;
      int dg = (g & 31) * 4, kg2 = (g >> 5) * 4;
      union { uint2 u; unsigned short s[4]; } a[4], o;
#pragma unroll
      for (int i2 = 0; i2 < 4; i2++) {
        int kr = sc + kg2 + i2; if (kr > 2047) kr = 2047;
        a[i2].u = *(const uint2*)&Vb[(size_t)kr * 128 + dg];
      }
#pragma unroll
      for (int j = 0; j < 4; j++) {
        int d = dg + j;
        int pb = ((kg2 >> 3) + (d >> 2)) & 7;
        o.s[0] = a[0].s[j]; o.s[1] = a[1].s[j];
        o.s[2] = a[2].s[j]; o.s[3] = a[3].s[j];
        *(uint2*)&VsT[d * VT_LD + pb * 8 + (kg2 & 7)] = o.u;
      }
    }
    __syncthreads();

    // --- S = Q @ K^T ---
    f32x4 sf[2][4];
#pragma unroll
    for (int mi = 0; mi < 2; mi++)
#pragma unroll
      for (int kt = 0; kt < 4; kt++) sf[mi][kt] = (f32x4){0.f, 0.f, 0.f, 0.f};
#pragma unroll
    for (int ks = 0; ks < 4; ks++)
#pragma unroll
      for (int kt = 0; kt < 4; kt++) {
        bf16x8 kf = *(const bf16x8*)&Ks[(kt * 16 + l16) * KS_LD + ks * 32 + quad * 8];
        sf[0][kt] = __builtin_amdgcn_mfma_f32_16x16x32_bf16(qf[0][ks], kf, sf[0][kt], 0, 0, 0);
        sf[1][kt] = __builtin_amdgcn_mfma_f32_16x16x32_bf16(qf[1][ks], kf, sf[1][kt], 0, 0, 0);
      }

    // --- P = exp2(S*SCL2) with causal mask, straight to LDS ---
    __bf16* prw = Pr[wave];
#pragma unroll
    for (int mi = 0; mi < 2; mi++)
#pragma unroll
      for (int kt = 0; kt < 4; kt++) {
        int key = sc + kt * 16 + l16;
#pragma unroll
        for (int r = 0; r < 4; r++) {
          int qrow = q0 + mi * 16 + quad * 4 + r;
          float p = (key <= qrow) ? exp2f(sf[mi][kt][r] * SCL2) : 0.f;
          prw[(mi * 16 + quad * 4 + r) * PR_LD + kt * 16 + l16] = (__bf16)p;
        }
      }

    // --- O += P @ V ; l += P @ 1 (rowsum via MFMA) ---
#pragma unroll
    for (int ks2 = 0; ks2 < 2; ks2++) {
      bf16x8 pf0 = *(const bf16x8*)&prw[(l16) * PR_LD + ks2 * 32 + quad * 8];
      bf16x8 pf1 = *(const bf16x8*)&prw[(16 + l16) * PR_LD + ks2 * 32 + quad * 8];
      lacc[0] = __builtin_amdgcn_mfma_f32_16x16x32_bf16(pf0, ones, lacc[0], 0, 0, 0);
      lacc[1] = __builtin_amdgcn_mfma_f32_16x16x32_bf16(pf1, ones, lacc[1], 0, 0, 0);
#pragma unroll
      for (int nt = 0; nt < 8; nt++) {
        int d = nt * 16 + l16;
        int pb = ((ks2 * 4 + quad) + (d >> 2)) & 7;
        bf16x8 vf = *(const bf16x8*)&VsT[d * VT_LD + pb * 8];
        oa[0][nt] = __builtin_amdgcn_mfma_f32_16x16x32_bf16(pf0, vf, oa[0][nt], 0, 0, 0);
        oa[1][nt] = __builtin_amdgcn_mfma_f32_16x16x32_bf16(pf1, vf, oa[1][nt], 0, 0, 0);
      }
    }
  }

  // epilogue: O[row] = oa / l   (l > 0: diagonal key always unmasked)
#pragma unroll
  for (int mi = 0; mi < 2; mi++)
#pragma unroll
    for (int r = 0; r < 4; r++) {
      float inv = 1.f / lacc[mi][r];
      size_t row = qgrow + mi * 16 + quad * 4 + r;
#pragma unroll
      for (int nt = 0; nt < 8; nt++)
        O[row * 2048 + h * 128 + nt * 16 + l16] = (__bf16)(oa[mi][nt][r] * inv);
    }
}

// ---------------------------------------------------------------------------
// Memory plan:
//   ws   : q / at (in-place)            16.78 MB
//   d_out: xb | WqT | WkT | WvT | k | v 28.3 MB    (dead before final GEMM)
// ---------------------------------------------------------------------------
extern "C" void kernel_launch(void* const* d_in, const int* in_sizes, int n_in,
                              void* d_out, int out_size, void* d_ws, size_t ws_size,
                              hipStream_t stream) {
  const float* x  = (const float*)d_in[0];
  const float* Wq = (const float*)d_in[1];
  const float* Wk = (const float*)d_in[2];
  const float* Wv = (const float*)d_in[3];
  const float* Wo = (const float*)d_in[4];
  float* out = (float*)d_out;

  __bf16* q   = (__bf16*)d_ws;
  char* ob = (char*)d_out;
  __bf16* xb  = (__bf16*)(ob);
  __bf16* WqT = (__bf16*)(ob + 16777216);
  __bf16* WkT = (__bf16*)(ob + 25165824);
  __bf16* WvT = (__bf16*)(ob + 25690112);
  __bf16* kb  = (__bf16*)(ob + 26214400);
  __bf16* vb  = (__bf16*)(ob + 27262976);

  dim3 blk(256);
  conv_bf16<<<4096, blk, 0, stream>>>(x, xb);
  transpose_w<<<dim3(32, 32), blk, 0, stream>>>(Wq, WqT, 2048, 2048);
  transpose_w<<<dim3(2, 32), blk, 0, stream>>>(Wk, WkT, 2048, 128);
  transpose_w<<<dim3(2, 32), blk, 0, stream>>>(Wv, WvT, 2048, 128);
  gemm_qkv<<<dim3(18, 32), blk, 0, stream>>>(xb, WqT, WkT, WvT, q, kb, vb);
  mqa_attn_mfma<<<dim3(64, 8, 1), blk, 0, stream>>>(q, kb, vb, q);
  gemm_out<<<dim3(16, 32), blk, 0, stream>>>(q, Wo, out);
}

// Round 8
// 299.352 us; speedup vs baseline: 6.6617x; 1.2673x over previous
//
#include <hip/hip_runtime.h>

typedef __bf16 bf16x8 __attribute__((ext_vector_type(8)));
typedef float f32x4 __attribute__((ext_vector_type(4)));

// Async global->LDS, 16B per lane. LDS dest is wave-uniform base + lane*16.
__device__ inline void gload16(const __bf16* g, __bf16* l) {
  __builtin_amdgcn_global_load_lds(
      (const __attribute__((address_space(1))) unsigned int*)g,
      (__attribute__((address_space(3))) unsigned int*)l, 16, 0, 0);
}

// ---------------------------------------------------------------------------
// Prep: fp32 -> bf16 elementwise (x). 8 elems/thread.
// ---------------------------------------------------------------------------
__global__ __launch_bounds__(256) void conv_bf16(
    const float* __restrict__ in, __bf16* __restrict__ out)
{
  size_t i = ((size_t)blockIdx.x * 256 + threadIdx.x) * 8;
  float4 a = *(const float4*)&in[i];
  float4 b = *(const float4*)&in[i + 4];
  bf16x8 h;
  h[0] = (__bf16)a.x; h[1] = (__bf16)a.y; h[2] = (__bf16)a.z; h[3] = (__bf16)a.w;
  h[4] = (__bf16)b.x; h[5] = (__bf16)b.y; h[6] = (__bf16)b.z; h[7] = (__bf16)b.w;
  *(bf16x8*)&out[i] = h;
}

// ---------------------------------------------------------------------------
// Prep: W fp32 [Kd][Nd] -> WT bf16 [Nd][Kd]. 64x64 LDS tile.
// ---------------------------------------------------------------------------
__global__ __launch_bounds__(256) void transpose_w(
    const float* __restrict__ W, __bf16* __restrict__ WT, int Kd, int Nd)
{
  __shared__ __bf16 Ts[64 * 72];
  const int tid = threadIdx.x;
  const int c0 = blockIdx.x * 64, r0 = blockIdx.y * 64;
#pragma unroll
  for (int i = 0; i < 4; i++) {
    int row = (tid >> 4) + i * 16, cv = (tid & 15) * 4;
    float4 w = *(const float4*)&W[(size_t)(r0 + row) * Nd + c0 + cv];
    Ts[(cv + 0) * 72 + row] = (__bf16)w.x;
    Ts[(cv + 1) * 72 + row] = (__bf16)w.y;
    Ts[(cv + 2) * 72 + row] = (__bf16)w.z;
    Ts[(cv + 3) * 72 + row] = (__bf16)w.w;
  }
  __syncthreads();
#pragma unroll
  for (int i = 0; i < 4; i++) {
    int n = (tid >> 4) + i * 16, kseg = (tid & 15) * 4;
    *(uint2*)&WT[(size_t)(c0 + n) * Kd + r0 + kseg] = *(uint2*)&Ts[n * 72 + kseg];
  }
}

// ---------------------------------------------------------------------------
// Fused q/k/v projection GEMM (pure bf16, m97 structure). Unchanged.
// ---------------------------------------------------------------------------
__global__ __launch_bounds__(256) void gemm_qkv(
    const __bf16* __restrict__ A, const __bf16* __restrict__ WqT,
    const __bf16* __restrict__ WkT, const __bf16* __restrict__ WvT,
    __bf16* __restrict__ Cq, __bf16* __restrict__ Ck, __bf16* __restrict__ Cv)
{
  __shared__ __align__(16) __bf16 Asl[128 * 32];
  __shared__ __align__(16) __bf16 Bsl[128 * 32];
  const int tid = threadIdx.x, wave = tid >> 6, lane = tid & 63;
  const int quad = lane >> 4, l16 = lane & 15;
  const int nb = blockIdx.x, m0 = blockIdx.y * 128;
  const __bf16* BT; __bf16* C; int ldC, c0;
  if (nb < 16)       { BT = WqT + (size_t)nb * 128 * 2048; C = Cq; ldC = 2048; c0 = nb * 128; }
  else if (nb == 16) { BT = WkT; C = Ck; ldC = 128; c0 = 0; }
  else               { BT = WvT; C = Cv; ldC = 128; c0 = 0; }
  const int wm = (wave >> 1) * 64, wn = (wave & 1) * 64;
  const int lrow = lane >> 2, lseg = (lane & 3) * 8;

  f32x4 acc[4][4];
#pragma unroll
  for (int i = 0; i < 4; i++)
#pragma unroll
    for (int j = 0; j < 4; j++) acc[i][j] = (f32x4){0.f, 0.f, 0.f, 0.f};

  for (int k0 = 0; k0 < 2048; k0 += 32) {
    __syncthreads();
#pragma unroll
    for (int c = 0; c < 2; c++) {
      int ch = wave * 2 + c;
      gload16(&A[(size_t)(m0 + ch * 16 + lrow) * 2048 + k0 + lseg], &Asl[ch * 512]);
      gload16(&BT[(size_t)(ch * 16 + lrow) * 2048 + k0 + lseg], &Bsl[ch * 512]);
    }
    __syncthreads();

    bf16x8 af[4], bf[4];
#pragma unroll
    for (int i = 0; i < 4; i++)
      af[i] = *(const bf16x8*)&Asl[(wm + i * 16 + l16) * 32 + quad * 8];
#pragma unroll
    for (int i = 0; i < 4; i++)
      bf[i] = *(const bf16x8*)&Bsl[(wn + i * 16 + l16) * 32 + quad * 8];
#pragma unroll
    for (int mi = 0; mi < 4; mi++)
#pragma unroll
      for (int ni = 0; ni < 4; ni++)
        acc[mi][ni] = __builtin_amdgcn_mfma_f32_16x16x32_bf16(
            af[mi], bf[ni], acc[mi][ni], 0, 0, 0);
  }

#pragma unroll
  for (int mi = 0; mi < 4; mi++)
#pragma unroll
    for (int ni = 0; ni < 4; ni++)
#pragma unroll
      for (int r = 0; r < 4; r++) {
        int row = m0 + wm + mi * 16 + quad * 4 + r;
        int col = c0 + wn + ni * 16 + l16;
        C[(size_t)row * ldC + col] = (__bf16)acc[mi][ni][r];
      }
}

// ---------------------------------------------------------------------------
// Final GEMM, pure-bf16 path: out fp32 = at bf16 @ WoT^T (WoT = Wo^T bf16).
// Same structure as gemm_qkv.
// ---------------------------------------------------------------------------
__global__ __launch_bounds__(256) void gemm_out_bt(
    const __bf16* __restrict__ A, const __bf16* __restrict__ BT,
    float* __restrict__ Cp)
{
  __shared__ __align__(16) __bf16 Asl[128 * 32];
  __shared__ __align__(16) __bf16 Bsl[128 * 32];
  const int tid = threadIdx.x, wave = tid >> 6, lane = tid & 63;
  const int quad = lane >> 4, l16 = lane & 15;
  const int n0 = blockIdx.x * 128, m0 = blockIdx.y * 128;
  const int wm = (wave >> 1) * 64, wn = (wave & 1) * 64;
  const int lrow = lane >> 2, lseg = (lane & 3) * 8;

  f32x4 acc[4][4];
#pragma unroll
  for (int i = 0; i < 4; i++)
#pragma unroll
    for (int j = 0; j < 4; j++) acc[i][j] = (f32x4){0.f, 0.f, 0.f, 0.f};

  for (int k0 = 0; k0 < 2048; k0 += 32) {
    __syncthreads();
#pragma unroll
    for (int c = 0; c < 2; c++) {
      int ch = wave * 2 + c;
      gload16(&A[(size_t)(m0 + ch * 16 + lrow) * 2048 + k0 + lseg], &Asl[ch * 512]);
      gload16(&BT[(size_t)(n0 + ch * 16 + lrow) * 2048 + k0 + lseg], &Bsl[ch * 512]);
    }
    __syncthreads();

    bf16x8 af[4], bf[4];
#pragma unroll
    for (int i = 0; i < 4; i++)
      af[i] = *(const bf16x8*)&Asl[(wm + i * 16 + l16) * 32 + quad * 8];
#pragma unroll
    for (int i = 0; i < 4; i++)
      bf[i] = *(const bf16x8*)&Bsl[(wn + i * 16 + l16) * 32 + quad * 8];
#pragma unroll
    for (int mi = 0; mi < 4; mi++)
#pragma unroll
      for (int ni = 0; ni < 4; ni++)
        acc[mi][ni] = __builtin_amdgcn_mfma_f32_16x16x32_bf16(
            af[mi], bf[ni], acc[mi][ni], 0, 0, 0);
  }

#pragma unroll
  for (int mi = 0; mi < 4; mi++)
#pragma unroll
    for (int ni = 0; ni < 4; ni++)
#pragma unroll
      for (int r = 0; r < 4; r++) {
        int row = m0 + wm + mi * 16 + quad * 4 + r;
        int col = n0 + wn + ni * 16 + l16;
        Cp[(size_t)row * 2048 + col] = acc[mi][ni][r];
      }
}

// ---------------------------------------------------------------------------
// Final GEMM, fallback (ws too small for WoT): out fp32 = at bf16 @ Wo fp32.
// Round-7 kernel verbatim.
// ---------------------------------------------------------------------------
__global__ __launch_bounds__(256) void gemm_out_f32b(
    const __bf16* __restrict__ A, const float* __restrict__ B,
    float* __restrict__ Cp)
{
  __shared__ __align__(16) __bf16 Asl[128 * 32];
  __shared__ __align__(16) __bf16 BsT[128 * 32];
  const int tid = threadIdx.x, wave = tid >> 6, lane = tid & 63;
  const int quad = lane >> 4, l16 = lane & 15;
  const int n0 = blockIdx.x * 128, m0 = blockIdx.y * 128;
  const int wm = (wave >> 1) * 64, wn = (wave & 1) * 64;
  const int lrow = lane >> 2, lseg = (lane & 3) * 8;
  const int kg = (tid >> 5) * 4, ng = (tid & 31) * 4;

  f32x4 acc[4][4];
#pragma unroll
  for (int i = 0; i < 4; i++)
#pragma unroll
    for (int j = 0; j < 4; j++) acc[i][j] = (f32x4){0.f, 0.f, 0.f, 0.f};

  for (int k0 = 0; k0 < 2048; k0 += 32) {
    __syncthreads();
#pragma unroll
    for (int c = 0; c < 2; c++) {
      int ch = wave * 2 + c;
      gload16(&A[(size_t)(m0 + ch * 16 + lrow) * 2048 + k0 + lseg], &Asl[ch * 512]);
    }
    __bf16 h[4][4];
#pragma unroll
    for (int i = 0; i < 4; i++) {
      float4 w = *(const float4*)&B[(size_t)(k0 + kg + i) * 2048 + n0 + ng];
      h[i][0] = (__bf16)w.x; h[i][1] = (__bf16)w.y;
      h[i][2] = (__bf16)w.z; h[i][3] = (__bf16)w.w;
    }
#pragma unroll
    for (int j = 0; j < 4; j++) {
      int n = ng + j;
      int pb = ((kg >> 3) + (n >> 2)) & 3;
      __bf16 o4[4] = {h[0][j], h[1][j], h[2][j], h[3][j]};
      *(uint2*)&BsT[n * 32 + pb * 8 + (kg & 7)] = *(uint2*)o4;
    }
    __syncthreads();

    bf16x8 af[4], bf[4];
#pragma unroll
    for (int i = 0; i < 4; i++)
      af[i] = *(const bf16x8*)&Asl[(wm + i * 16 + l16) * 32 + quad * 8];
#pragma unroll
    for (int i = 0; i < 4; i++) {
      int n = wn + i * 16 + l16;
      int pb = (quad + (n >> 2)) & 3;
      bf[i] = *(const bf16x8*)&BsT[n * 32 + pb * 8];
    }
#pragma unroll
    for (int mi = 0; mi < 4; mi++)
#pragma unroll
      for (int ni = 0; ni < 4; ni++)
        acc[mi][ni] = __builtin_amdgcn_mfma_f32_16x16x32_bf16(
            af[mi], bf[ni], acc[mi][ni], 0, 0, 0);
  }

#pragma unroll
  for (int mi = 0; mi < 4; mi++)
#pragma unroll
    for (int ni = 0; ni < 4; ni++)
#pragma unroll
      for (int r = 0; r < 4; r++) {
        int row = m0 + wm + mi * 16 + quad * 4 + r;
        int col = n0 + wn + ni * 16 + l16;
        Cp[(size_t)row * 2048 + col] = acc[mi][ni][r];
      }
}

// ---------------------------------------------------------------------------
// MQA causal flash attention, MFMA, fixed-base streaming softmax.
// ROUND 8: compute S^T = MFMA(A=K-frag, B=Q-frag) — A/B frags have identical
// lane mappings, so the already-loaded Q regs serve as B directly. S^T's
// C-layout puts 4 CONTIGUOUS keys (quad*4+r) in each lane's regs at one qrow
// (l16), so P stores become 8 x b64 (was 32 x b16). Causal mask only applies
// to the last chunk of each q-tile (uniform branch).
// l = P @ ones via MFMA (no cross-lane reductions). IN-PLACE SAFE Q==O.
// ---------------------------------------------------------------------------
#define KS_LD 136
#define VT_LD 72
#define PR_LD 72

__global__ __launch_bounds__(256) void mqa_attn_mfma(
    const __bf16* Q, const __bf16* __restrict__ Km,
    const __bf16* __restrict__ Vm, __bf16* O)
{
  __shared__ __align__(16) __bf16 Ks[64 * KS_LD];
  __shared__ __align__(16) __bf16 VsT[128 * VT_LD];
  __shared__ __align__(16) __bf16 Pr[4][32 * PR_LD];

  const int tid = threadIdx.x, wave = tid >> 6, lane = tid & 63;
  const int quad = lane >> 4, l16 = lane & 15;
  const int t = blockIdx.x >> 1, bat = blockIdx.x & 1;
  const int hg = blockIdx.y & 3, flip = blockIdx.y >> 2;
  const int qt = flip ? (63 - t) : t;
  const int h = hg * 4 + wave;
  const int q0 = qt * 32;
  const size_t qgrow = (size_t)bat * 2048 + q0;
  const float SCL2 = 0.08838834764831845f * 1.4426950408889634f;  // scale*log2e

  // Q regs: lane holds Q[qrow=l16(+16mi)][d=ks*32+quad*8+j] — serves as the
  // B-frag of Q (B[k=d][n=qrow]) for the S^T MFMA.
  bf16x8 qf[2][4];
#pragma unroll
  for (int mi = 0; mi < 2; mi++)
#pragma unroll
    for (int ks = 0; ks < 4; ks++)
      qf[mi][ks] = *(const bf16x8*)(Q + (qgrow + mi * 16 + l16) * 2048 +
                                    h * 128 + ks * 32 + quad * 8);

  bf16x8 ones;
#pragma unroll
  for (int i = 0; i < 8; i++) ones[i] = (__bf16)1.0f;

  f32x4 oa[2][8];
#pragma unroll
  for (int mi = 0; mi < 2; mi++)
#pragma unroll
    for (int nt = 0; nt < 8; nt++) oa[mi][nt] = (f32x4){0.f, 0.f, 0.f, 0.f};
  f32x4 lacc[2];
  lacc[0] = (f32x4){0.f, 0.f, 0.f, 0.f};
  lacc[1] = (f32x4){0.f, 0.f, 0.f, 0.f};

  const __bf16* Kb = Km + (size_t)bat * 2048 * 128;
  const __bf16* Vb = Vm + (size_t)bat * 2048 * 128;
  const int qmax = q0 + 31;

  for (int sc = 0; sc <= qmax; sc += 64) {
    __syncthreads();
    // --- stage K[key][d] ---
#pragma unroll
    for (int i = 0; i < 4; i++) {
      int v = tid + i * 256;
      int row = v >> 4, dseg = (v & 15) * 8;
      int kr = sc + row; if (kr > 2047) kr = 2047;
      *(bf16x8*)&Ks[row * KS_LD + dseg] =
          *(const bf16x8*)&Kb[(size_t)kr * 128 + dseg];
    }
    // --- stage V transposed [d][key], rotated 8-key blocks ---
#pragma unroll
    for (int i = 0; i < 2; i++) {
      int g = tid + i * 256;
      int dg = (g & 31) * 4, kg2 = (g >> 5) * 4;
      union { uint2 u; unsigned short s[4]; } a[4], o;
#pragma unroll
      for (int i2 = 0; i2 < 4; i2++) {
        int kr = sc + kg2 + i2; if (kr > 2047) kr = 2047;
        a[i2].u = *(const uint2*)&Vb[(size_t)kr * 128 + dg];
      }
#pragma unroll
      for (int j = 0; j < 4; j++) {
        int d = dg + j;
        int pb = ((kg2 >> 3) + (d >> 2)) & 7;
        o.s[0] = a[0].s[j]; o.s[1] = a[1].s[j];
        o.s[2] = a[2].s[j]; o.s[3] = a[3].s[j];
        *(uint2*)&VsT[d * VT_LD + pb * 8 + (kg2 & 7)] = o.u;
      }
    }
    __syncthreads();

    // --- S^T = K @ Q^T : D reg r = S^T[key=kt*16+quad*4+r][qrow=l16(+16mi)] ---
    f32x4 sf[2][4];
#pragma unroll
    for (int mi = 0; mi < 2; mi++)
#pragma unroll
      for (int kt = 0; kt < 4; kt++) sf[mi][kt] = (f32x4){0.f, 0.f, 0.f, 0.f};
#pragma unroll
    for (int ks = 0; ks < 4; ks++)
#pragma unroll
      for (int kt = 0; kt < 4; kt++) {
        bf16x8 kf = *(const bf16x8*)&Ks[(kt * 16 + l16) * KS_LD + ks * 32 + quad * 8];
        sf[0][kt] = __builtin_amdgcn_mfma_f32_16x16x32_bf16(kf, qf[0][ks], sf[0][kt], 0, 0, 0);
        sf[1][kt] = __builtin_amdgcn_mfma_f32_16x16x32_bf16(kf, qf[1][ks], sf[1][kt], 0, 0, 0);
      }

    // --- P = exp2(S*SCL2), Pr[qrow][key] via b64 (4 contiguous keys/reg) ---
    __bf16* prw = Pr[wave];
    if (sc + 64 > q0) {  // uniform: only the diagonal chunk needs the mask
#pragma unroll
      for (int mi = 0; mi < 2; mi++) {
        int qrow = q0 + mi * 16 + l16;
#pragma unroll
        for (int kt = 0; kt < 4; kt++) {
          int kbase = sc + kt * 16 + quad * 4;
          __bf16 h4[4];
#pragma unroll
          for (int r = 0; r < 4; r++) {
            float p = (kbase + r <= qrow) ? exp2f(sf[mi][kt][r] * SCL2) : 0.f;
            h4[r] = (__bf16)p;
          }
          *(uint2*)&prw[(mi * 16 + l16) * PR_LD + kt * 16 + quad * 4] = *(uint2*)h4;
        }
      }
    } else {
#pragma unroll
      for (int mi = 0; mi < 2; mi++)
#pragma unroll
        for (int kt = 0; kt < 4; kt++) {
          __bf16 h4[4];
#pragma unroll
          for (int r = 0; r < 4; r++) h4[r] = (__bf16)exp2f(sf[mi][kt][r] * SCL2);
          *(uint2*)&prw[(mi * 16 + l16) * PR_LD + kt * 16 + quad * 4] = *(uint2*)h4;
        }
    }

    // --- O += P @ V ; l += P @ 1 (rowsum via MFMA) ---
#pragma unroll
    for (int ks2 = 0; ks2 < 2; ks2++) {
      bf16x8 pf0 = *(const bf16x8*)&prw[(l16) * PR_LD + ks2 * 32 + quad * 8];
      bf16x8 pf1 = *(const bf16x8*)&prw[(16 + l16) * PR_LD + ks2 * 32 + quad * 8];
      lacc[0] = __builtin_amdgcn_mfma_f32_16x16x32_bf16(pf0, ones, lacc[0], 0, 0, 0);
      lacc[1] = __builtin_amdgcn_mfma_f32_16x16x32_bf16(pf1, ones, lacc[1], 0, 0, 0);
#pragma unroll
      for (int nt = 0; nt < 8; nt++) {
        int d = nt * 16 + l16;
        int pb = ((ks2 * 4 + quad) + (d >> 2)) & 7;
        bf16x8 vf = *(const bf16x8*)&VsT[d * VT_LD + pb * 8];
        oa[0][nt] = __builtin_amdgcn_mfma_f32_16x16x32_bf16(pf0, vf, oa[0][nt], 0, 0, 0);
        oa[1][nt] = __builtin_amdgcn_mfma_f32_16x16x32_bf16(pf1, vf, oa[1][nt], 0, 0, 0);
      }
    }
  }

  // epilogue: O[row] = oa / l   (l > 0: diagonal key always unmasked)
#pragma unroll
  for (int mi = 0; mi < 2; mi++)
#pragma unroll
    for (int r = 0; r < 4; r++) {
      float inv = 1.f / lacc[mi][r];
      size_t row = qgrow + mi * 16 + quad * 4 + r;
#pragma unroll
      for (int nt = 0; nt < 8; nt++)
        O[row * 2048 + h * 128 + nt * 16 + l16] = (__bf16)(oa[mi][nt][r] * inv);
    }
}

// ---------------------------------------------------------------------------
// Memory plan:
//   ws   : q / at (in-place) 16.78 MB | WoT 8.39 MB (only if ws_size allows)
//   d_out: xb | WqT | WkT | WvT | k | v 28.3 MB  (dead before final GEMM)
// ---------------------------------------------------------------------------
extern "C" void kernel_launch(void* const* d_in, const int* in_sizes, int n_in,
                              void* d_out, int out_size, void* d_ws, size_t ws_size,
                              hipStream_t stream) {
  const float* x  = (const float*)d_in[0];
  const float* Wq = (const float*)d_in[1];
  const float* Wk = (const float*)d_in[2];
  const float* Wv = (const float*)d_in[3];
  const float* Wo = (const float*)d_in[4];
  float* out = (float*)d_out;

  __bf16* q   = (__bf16*)d_ws;
  __bf16* WoT = (__bf16*)((char*)d_ws + 16777216);
  const bool have_wot = ws_size >= (size_t)(16777216 + 8388608);

  char* ob = (char*)d_out;
  __bf16* xb  = (__bf16*)(ob);
  __bf16* WqT = (__bf16*)(ob + 16777216);
  __bf16* WkT = (__bf16*)(ob + 25165824);
  __bf16* WvT = (__bf16*)(ob + 25690112);
  __bf16* kb  = (__bf16*)(ob + 26214400);
  __bf16* vb  = (__bf16*)(ob + 27262976);

  dim3 blk(256);
  conv_bf16<<<4096, blk, 0, stream>>>(x, xb);
  transpose_w<<<dim3(32, 32), blk, 0, stream>>>(Wq, WqT, 2048, 2048);
  transpose_w<<<dim3(2, 32), blk, 0, stream>>>(Wk, WkT, 2048, 128);
  transpose_w<<<dim3(2, 32), blk, 0, stream>>>(Wv, WvT, 2048, 128);
  if (have_wot)
    transpose_w<<<dim3(32, 32), blk, 0, stream>>>(Wo, WoT, 2048, 2048);
  gemm_qkv<<<dim3(18, 32), blk, 0, stream>>>(xb, WqT, WkT, WvT, q, kb, vb);
  mqa_attn_mfma<<<dim3(64, 8, 1), blk, 0, stream>>>(q, kb, vb, q);
  if (have_wot)
    gemm_out_bt<<<dim3(16, 32), blk, 0, stream>>>(q, WoT, out);
  else
    gemm_out_f32b<<<dim3(16, 32), blk, 0, stream>>>(q, Wo, out);
}